// Round 1
// baseline (1035.768 us; speedup 1.0000x reference)
//
#include <hip/hip_runtime.h>
#include <math.h>

#define Hh 16
#define DH 64
#define MAXREL 16
#define NR 33

// ---------------- GEMM: C[M,N] = A[M,K] @ W[K,N] + bias[N] ----------------
#define GT 64
#define GBK 16

__global__ __launch_bounds__(256)
void gemm_bias(const float* __restrict__ A, const float* __restrict__ W,
               const float* __restrict__ bias, float* __restrict__ C,
               int M, int N, int K) {
    __shared__ float As[GBK][GT + 1];
    __shared__ float Bs[GBK][GT + 1];
    const int tid = threadIdx.x;
    const int tx = tid & 15;   // n micro-tile
    const int ty = tid >> 4;   // m micro-tile
    const int bm = blockIdx.y * GT;
    const int bn = blockIdx.x * GT;
    float c[4][4] = {};
    for (int kk = 0; kk < K; kk += GBK) {
        #pragma unroll
        for (int r = 0; r < 4; ++r) {
            int row = (tid >> 4) + 16 * r;   // 0..63
            int col = tid & 15;              // 0..15
            As[col][row] = A[(size_t)(bm + row) * K + kk + col];
        }
        #pragma unroll
        for (int r = 0; r < 4; ++r) {
            int row = (tid >> 6) + 4 * r;    // 0..15
            int col = tid & 63;              // 0..63
            Bs[row][col] = W[(size_t)(kk + row) * N + bn + col];
        }
        __syncthreads();
        #pragma unroll
        for (int k2 = 0; k2 < GBK; ++k2) {
            float a[4], b[4];
            #pragma unroll
            for (int i = 0; i < 4; ++i) a[i] = As[k2][ty * 4 + i];
            #pragma unroll
            for (int j = 0; j < 4; ++j) b[j] = Bs[k2][tx * 4 + j];
            #pragma unroll
            for (int i = 0; i < 4; ++i)
                #pragma unroll
                for (int j = 0; j < 4; ++j)
                    c[i][j] = fmaf(a[i], b[j], c[i][j]);
        }
        __syncthreads();
    }
    #pragma unroll
    for (int i = 0; i < 4; ++i) {
        int row = bm + ty * 4 + i;
        #pragma unroll
        for (int j = 0; j < 4; ++j) {
            int col = bn + tx * 4 + j;
            C[(size_t)row * N + col] = c[i][j] + bias[col];
        }
    }
}

// ---------------- Flash-style attention with Shaw relative positions ------
// One workgroup = (b, h, block of QB q-rows). Online softmax over K tiles.
// attn2 via qr[qi][bucket] (precomputed q . rel_k[r]); rel_v folded into PV:
// out = sum_k p * (v[k,:] + rel_v[bucket(q,k),:]).
#define QB 16
#define KT 64

__global__ __launch_bounds__(256)
void attn_rel(const float* __restrict__ q, const float* __restrict__ k,
              const float* __restrict__ v, const float* __restrict__ relk,
              const float* __restrict__ relv, float* __restrict__ x,
              int B, int S) {
    __shared__ float q_lds[QB][DH + 1];
    __shared__ float k_lds[KT][DH + 1];
    __shared__ float v_lds[KT][DH + 1];
    __shared__ float rv_lds[NR][DH + 1];
    __shared__ float p_lds[QB][KT + 1];
    __shared__ float qr_lds[QB][NR + 3];

    const int tid = threadIdx.x;
    const int qi = tid >> 4;          // q-row within block: 0..15
    const int c  = tid & 15;          // column group: 0..15
    const int nqb = S / QB;
    const int blk = blockIdx.x;
    const int qb = blk % nqb;
    const int h  = (blk / nqb) % Hh;
    const int b  = blk / (nqb * Hh);
    const int Dm = Hh * DH;
    const size_t base = (size_t)b * S * Dm;
    const int q_abs = qb * QB + qi;

    // stage q block: QB x DH
    #pragma unroll
    for (int r = 0; r < 4; ++r) {
        int idx = tid + 256 * r;
        int row = idx >> 6, col = idx & 63;
        q_lds[row][col] = q[base + (size_t)(qb * QB + row) * Dm + h * DH + col];
    }
    // stage rel_v: NR x DH
    for (int idx = tid; idx < NR * DH; idx += 256) {
        rv_lds[idx >> 6][idx & 63] = relv[idx];
    }
    __syncthreads();
    // qr[qi][r] = q_row . rel_k[r]
    for (int t = tid; t < QB * NR; t += 256) {
        int row = t / NR, rr = t % NR;
        float s = 0.f;
        for (int d = 0; d < DH; ++d) s = fmaf(q_lds[row][d], relk[rr * DH + d], s);
        qr_lds[row][rr] = s;
    }
    __syncthreads();

    float m = -1e30f, l = 0.f;
    float acc[4] = {0.f, 0.f, 0.f, 0.f};
    const float inv_scale = 0.125f;   // 1/sqrt(dh)

    for (int kt = 0; kt < S; kt += KT) {
        // stage k,v tiles (KT x DH each)
        #pragma unroll
        for (int r = 0; r < 16; ++r) {
            int idx = tid + 256 * r;
            int row = idx >> 6, col = idx & 63;
            size_t g = base + (size_t)(kt + row) * Dm + h * DH + col;
            k_lds[row][col] = k[g];
            v_lds[row][col] = v[g];
        }
        __syncthreads();

        // scores: thread (qi,c) computes k columns c + 16*s2
        float dotv[4] = {0.f, 0.f, 0.f, 0.f};
        for (int d = 0; d < DH; ++d) {
            float qd = q_lds[qi][d];
            #pragma unroll
            for (int s2 = 0; s2 < 4; ++s2)
                dotv[s2] = fmaf(qd, k_lds[c + 16 * s2][d], dotv[s2]);
        }
        float tmax = -1e30f;
        float sv[4];
        #pragma unroll
        for (int s2 = 0; s2 < 4; ++s2) {
            int kk = c + 16 * s2;
            int dist = kt + kk - q_abs;
            int bucket = min(max(dist, -MAXREL), MAXREL) + MAXREL;
            float val = (dotv[s2] + qr_lds[qi][bucket]) * inv_scale;
            sv[s2] = val;
            tmax = fmaxf(tmax, val);
        }
        #pragma unroll
        for (int off = 8; off >= 1; off >>= 1)
            tmax = fmaxf(tmax, __shfl_xor(tmax, off, 16));
        float m_new = fmaxf(m, tmax);
        float factor = __expf(m - m_new);
        float psum = 0.f;
        #pragma unroll
        for (int s2 = 0; s2 < 4; ++s2) {
            float p = __expf(sv[s2] - m_new);
            p_lds[qi][c + 16 * s2] = p;
            psum += p;
        }
        #pragma unroll
        for (int off = 8; off >= 1; off >>= 1)
            psum += __shfl_xor(psum, off, 16);
        l = l * factor + psum;
        m = m_new;
        #pragma unroll
        for (int j = 0; j < 4; ++j) acc[j] *= factor;
        __syncthreads();   // p_lds visible to whole block

        // PV: thread (qi,c) owns output dims c*4 .. c*4+3
        for (int kk = 0; kk < KT; ++kk) {
            float p = p_lds[qi][kk];
            int dist = kt + kk - q_abs;
            int bucket = min(max(dist, -MAXREL), MAXREL) + MAXREL;
            #pragma unroll
            for (int j = 0; j < 4; ++j) {
                int d = c * 4 + j;
                acc[j] = fmaf(p, v_lds[kk][d] + rv_lds[bucket][d], acc[j]);
            }
        }
        __syncthreads();   // before next tile overwrites k/v/p
    }
    float invl = 1.f / l;
    size_t o = base + (size_t)q_abs * Dm + h * DH + c * 4;
    #pragma unroll
    for (int j = 0; j < 4; ++j) x[o + j] = acc[j] * invl;
}

// ---------------------------------------------------------------------------
extern "C" void kernel_launch(void* const* d_in, const int* in_sizes, int n_in,
                              void* d_out, int out_size, void* d_ws, size_t ws_size,
                              hipStream_t stream) {
    const float* query = (const float*)d_in[0];
    const float* key   = (const float*)d_in[1];
    const float* value = (const float*)d_in[2];
    const float* Wq    = (const float*)d_in[3];
    const float* bq    = (const float*)d_in[4];
    const float* Wk    = (const float*)d_in[5];
    const float* bk    = (const float*)d_in[6];
    const float* Wv    = (const float*)d_in[7];
    const float* bv    = (const float*)d_in[8];
    const float* Wo    = (const float*)d_in[9];
    const float* bo    = (const float*)d_in[10];
    const float* rel_k = (const float*)d_in[11];
    const float* rel_v = (const float*)d_in[12];

    const int B = 2, S = 1024, D = 1024;
    const int M = B * S;
    const size_t elems = (size_t)M * D;

    float* q_ws = (float*)d_ws;
    float* k_ws = q_ws + elems;
    float* v_ws = k_ws + elems;
    float* x_ws = v_ws + elems;

    dim3 ggrid(D / GT, M / GT);
    gemm_bias<<<ggrid, 256, 0, stream>>>(query, Wq, bq, q_ws, M, D, D);
    gemm_bias<<<ggrid, 256, 0, stream>>>(key,   Wk, bk, k_ws, M, D, D);
    gemm_bias<<<ggrid, 256, 0, stream>>>(value, Wv, bv, v_ws, M, D, D);

    const int nqb = S / QB;
    attn_rel<<<B * Hh * nqb, 256, 0, stream>>>(q_ws, k_ws, v_ws, rel_k, rel_v,
                                               x_ws, B, S);

    gemm_bias<<<ggrid, 256, 0, stream>>>(x_ws, Wo, bo, (float*)d_out, M, D, D);
}

// Round 5
// 449.259 us; speedup vs baseline: 2.3055x; 2.3055x over previous
//
#include <hip/hip_runtime.h>
#include <math.h>

#define Hh 16
#define DH 64
#define NR 33

typedef short s16x8 __attribute__((ext_vector_type(8)));
typedef float f32x4 __attribute__((ext_vector_type(4)));

static __device__ __forceinline__ short f2bf(float f) {
    unsigned u = __float_as_uint(f);
    u += 0x7fff + ((u >> 16) & 1);          // round-to-nearest-even
    return (short)(u >> 16);
}

// MFMA with hazard nops INSIDE the asm block so the output dependency
// orders every consumer after the wait-states (a separate `asm volatile`
// nop block has no dep on the accumulator and the scheduler may move
// VALU/ds consumers between the MFMA and the nops -> stale reads).
//   _chain: leading s_nop only (next consumer is MFMA SrcC accumulate: 0 wait)
//   _last : + 16 trailing wait-states (>= 4-pass XDL write->VALU/LDS-read req)
static __device__ __forceinline__ void mfma_chain(f32x4& c, const s16x8& a, const s16x8& b) {
    asm("s_nop 3\n\tv_mfma_f32_16x16x32_bf16 %0, %1, %2, %0"
        : "+v"(c) : "v"(a), "v"(b));
}
static __device__ __forceinline__ void mfma_last(f32x4& c, const s16x8& a, const s16x8& b) {
    asm("s_nop 3\n\tv_mfma_f32_16x16x32_bf16 %0, %1, %2, %0\n\ts_nop 7\n\ts_nop 7"
        : "+v"(c) : "v"(a), "v"(b));
}

// ---------------- GEMM: C[M,N] = A[M,K] @ W[K,N] + bias[N] (fp32) ----------
#define GT 64
#define GBK 16

__global__ __launch_bounds__(256)
void gemm_bias(const float* __restrict__ A, const float* __restrict__ W,
               const float* __restrict__ bias, float* __restrict__ C,
               int M, int N, int K) {
    __shared__ float As[GBK][GT + 1];
    __shared__ float Bs[GBK][GT + 1];
    const int tid = threadIdx.x;
    const int tx = tid & 15;
    const int ty = tid >> 4;
    const int bm = blockIdx.y * GT;
    const int bn = blockIdx.x * GT;
    float c[4][4] = {};
    for (int kk = 0; kk < K; kk += GBK) {
        #pragma unroll
        for (int r = 0; r < 4; ++r) {
            int row = (tid >> 4) + 16 * r;
            int col = tid & 15;
            As[col][row] = A[(size_t)(bm + row) * K + kk + col];
        }
        #pragma unroll
        for (int r = 0; r < 4; ++r) {
            int row = (tid >> 6) + 4 * r;
            int col = tid & 63;
            Bs[row][col] = W[(size_t)(kk + row) * N + bn + col];
        }
        __syncthreads();
        #pragma unroll
        for (int k2 = 0; k2 < GBK; ++k2) {
            float a[4], b[4];
            #pragma unroll
            for (int i = 0; i < 4; ++i) a[i] = As[k2][ty * 4 + i];
            #pragma unroll
            for (int j = 0; j < 4; ++j) b[j] = Bs[k2][tx * 4 + j];
            #pragma unroll
            for (int i = 0; i < 4; ++i)
                #pragma unroll
                for (int j = 0; j < 4; ++j)
                    c[i][j] = fmaf(a[i], b[j], c[i][j]);
        }
        __syncthreads();
    }
    #pragma unroll
    for (int i = 0; i < 4; ++i) {
        int row = bm + ty * 4 + i;
        #pragma unroll
        for (int j = 0; j < 4; ++j) {
            int col = bn + tx * 4 + j;
            C[(size_t)row * N + col] = c[i][j] + bias[col];
        }
    }
}

// ---------------- MFMA attention with Shaw relative positions ---------------
// Block = (b,h, 64 q-rows), 4 waves x 16 q-rows. No online softmax (scores
// bounded: |q.k|/8 <= ~8, exp2 in fp32 safe). rel_k bias via qr = Qs@relk^T
// (MFMA). rel_v via bucket-histogram W[q][33] (band buckets 1..31 have a
// unique k -> direct store; buckets 0/32 are predicated sums, shfl-reduced),
// then R = W@rv fp32 at the end.
#define KSTR 72    // shorts per LDS row (144B, 16B aligned)
#define QRSTR 49
#define RVSTR 68

__global__ __launch_bounds__(256)
void attn_mfma(const float* __restrict__ qg, const float* __restrict__ kg,
               const float* __restrict__ vg, const float* __restrict__ relk,
               const float* __restrict__ relv, float* __restrict__ xg) {
    __shared__ __align__(16) short k_s[64 * KSTR];
    __shared__ __align__(16) short vt_s[64 * KSTR];
    __shared__ __align__(16) short p_s[4][16 * KSTR];
    __shared__ float qr_s[64 * QRSTR];
    __shared__ float W_s[64 * NR];
    __shared__ __align__(16) unsigned char relbuf[NR * RVSTR * 4]; // 8976B

    short* rel_bf = (short*)relbuf;   // [48][KSTR] bf16 (start of block)
    float* rv_s   = (float*)relbuf;   // [33][RVSTR] fp32 (epilogue)

    const int S = 1024, Dm = 1024;
    const int tid = threadIdx.x;
    const int wave = tid >> 6;
    const int lane = tid & 63;
    const int g = lane >> 4;      // k-group 0..3
    const int r = lane & 15;      // row/col within 16

    const int blk = blockIdx.x;
    const int bh = blk & 31;      // same bh -> same XCD (blk%8 fixed) for L2 reuse
    const int qb = blk >> 5;
    const int b = bh >> 4, h = bh & 15;
    const size_t base = (size_t)b * S * Dm + h * DH;
    const int qw = qb * 64 + wave * 16;   // wave's first q row

    // rel_k -> bf16 LDS (rows 33..47 zeroed); scale is carried by Q.
    for (int idx = tid; idx < 48 * 64; idx += 256) {
        int row = idx >> 6, col = idx & 63;
        float val = (row < NR) ? relk[row * 64 + col] : 0.f;
        rel_bf[row * KSTR + col] = f2bf(val);
    }
    for (int idx = tid; idx < 64 * NR; idx += 256) W_s[idx] = 0.f;
    __syncthreads();

    // Q fragments, pre-scaled by log2(e)/sqrt(dh) so p = exp2(s + qr)
    const float SCL = 0.18033688f;  // log2(e)/8
    s16x8 qf[2];
    #pragma unroll
    for (int kf = 0; kf < 2; ++kf) {
        const float* qp = qg + base + (size_t)(qw + r) * Dm + kf * 32 + g * 8;
        float4 a = *(const float4*)qp;
        float4 c = *(const float4*)(qp + 4);
        s16x8 t;
        t[0] = f2bf(a.x * SCL); t[1] = f2bf(a.y * SCL);
        t[2] = f2bf(a.z * SCL); t[3] = f2bf(a.w * SCL);
        t[4] = f2bf(c.x * SCL); t[5] = f2bf(c.y * SCL);
        t[6] = f2bf(c.z * SCL); t[7] = f2bf(c.w * SCL);
        qf[kf] = t;
    }

    // qr[q][bucket] = Qs . relk[bucket]  (3 col-tiles of 16, cols>=33 unused)
    #pragma unroll
    for (int ct = 0; ct < 3; ++ct) {
        f32x4 c = {0.f, 0.f, 0.f, 0.f};
        s16x8 bf0 = *(const s16x8*)&rel_bf[(ct * 16 + r) * KSTR + g * 8];
        s16x8 bf1 = *(const s16x8*)&rel_bf[(ct * 16 + r) * KSTR + 32 + g * 8];
        mfma_chain(c, qf[0], bf0);
        mfma_last(c, qf[1], bf1);     // c safely readable after this block
        #pragma unroll
        for (int j = 0; j < 4; ++j)
            qr_s[(wave * 16 + g * 4 + j) * QRSTR + ct * 16 + r] = c[j];
    }

    f32x4 acc[4] = {};
    float l_acc[4] = {0.f, 0.f, 0.f, 0.f};
    float pre[4]   = {0.f, 0.f, 0.f, 0.f};
    float suf[4]   = {0.f, 0.f, 0.f, 0.f};

    for (int kt = 0; kt < S; kt += 64) {
        __syncthreads();   // previous tile's reads complete
        // stage K (row-major) and V^T (d-major) as bf16
        #pragma unroll
        for (int i = 0; i < 4; ++i) {
            int idx = tid + 256 * i;
            int row = idx >> 4, c4 = idx & 15;
            const float* kp = kg + base + (size_t)(kt + row) * Dm + c4 * 4;
            const float* vp = vg + base + (size_t)(kt + row) * Dm + c4 * 4;
            float4 kv = *(const float4*)kp;
            float4 vv = *(const float4*)vp;
            short* kd = &k_s[row * KSTR + c4 * 4];
            kd[0] = f2bf(kv.x); kd[1] = f2bf(kv.y);
            kd[2] = f2bf(kv.z); kd[3] = f2bf(kv.w);
            vt_s[(c4 * 4 + 0) * KSTR + row] = f2bf(vv.x);
            vt_s[(c4 * 4 + 1) * KSTR + row] = f2bf(vv.y);
            vt_s[(c4 * 4 + 2) * KSTR + row] = f2bf(vv.z);
            vt_s[(c4 * 4 + 3) * KSTR + row] = f2bf(vv.w);
        }
        __syncthreads();

        // QK^T + bias + exp2 + bucket bookkeeping
        #pragma unroll
        for (int kc = 0; kc < 4; ++kc) {
            f32x4 s = {0.f, 0.f, 0.f, 0.f};
            s16x8 k0 = *(const s16x8*)&k_s[(kc * 16 + r) * KSTR + g * 8];
            s16x8 k1 = *(const s16x8*)&k_s[(kc * 16 + r) * KSTR + 32 + g * 8];
            mfma_chain(s, qf[0], k0);
            mfma_last(s, qf[1], k1);  // s safely readable after this block
            int k_abs = kt + kc * 16 + r;
            #pragma unroll
            for (int j = 0; j < 4; ++j) {
                int qrow = wave * 16 + g * 4 + j;       // block-local q
                int dist = k_abs - (qb * 64 + qrow);
                int bkt = min(max(dist, -16), 16) + 16;
                float val = s[j] + qr_s[qrow * QRSTR + bkt];
                float p = exp2f(val);
                l_acc[j] += p;
                if (dist <= -16)      pre[j] += p;
                else if (dist >= 16)  suf[j] += p;
                else                  W_s[qrow * NR + bkt] = p;  // unique (q,k)
                p_s[wave][(g * 4 + j) * KSTR + kc * 16 + r] = f2bf(p);
            }
        }

        // PV: acc[q][d] += P . V  (A-frags from p_s, B-frags from vt_s).
        // acc is only read in the epilogue (hundreds of instrs away) -> chains.
        s16x8 pa0 = *(const s16x8*)&p_s[wave][r * KSTR + g * 8];
        s16x8 pa1 = *(const s16x8*)&p_s[wave][r * KSTR + 32 + g * 8];
        #pragma unroll
        for (int dc = 0; dc < 4; ++dc) {
            s16x8 v0 = *(const s16x8*)&vt_s[(dc * 16 + r) * KSTR + g * 8];
            s16x8 v1 = *(const s16x8*)&vt_s[(dc * 16 + r) * KSTR + 32 + g * 8];
            mfma_chain(acc[dc], pa0, v0);
            mfma_chain(acc[dc], pa1, v1);
        }
    }

    // reduce per-row stats across the 16 lanes of each g-group
    #pragma unroll
    for (int j = 0; j < 4; ++j) {
        #pragma unroll
        for (int m = 1; m < 16; m <<= 1) {
            l_acc[j] += __shfl_xor(l_acc[j], m, 16);
            pre[j]   += __shfl_xor(pre[j], m, 16);
            suf[j]   += __shfl_xor(suf[j], m, 16);
        }
    }
    if (r == 0) {
        #pragma unroll
        for (int j = 0; j < 4; ++j) {
            int qrow = wave * 16 + g * 4 + j;
            W_s[qrow * NR + 0]  = pre[j];
            W_s[qrow * NR + 32] = suf[j];
        }
    }

    __syncthreads();
    // load rel_v fp32 over relbuf
    for (int idx = tid; idx < NR * 64; idx += 256)
        rv_s[(idx >> 6) * RVSTR + (idx & 63)] = relv[idx];
    __syncthreads();

    // R = W @ rv, combine, normalize, write x
    float R[4][4] = {};
    for (int rr = 0; rr < NR; ++rr) {
        float rvv[4];
        #pragma unroll
        for (int dc = 0; dc < 4; ++dc) rvv[dc] = rv_s[rr * RVSTR + dc * 16 + r];
        #pragma unroll
        for (int j = 0; j < 4; ++j) {
            float w = W_s[(wave * 16 + g * 4 + j) * NR + rr];
            #pragma unroll
            for (int dc = 0; dc < 4; ++dc) R[j][dc] = fmaf(w, rvv[dc], R[j][dc]);
        }
    }
    #pragma unroll
    for (int j = 0; j < 4; ++j) {
        float invl = 1.f / l_acc[j];
        size_t o = base + (size_t)(qw + g * 4 + j) * Dm;
        #pragma unroll
        for (int dc = 0; dc < 4; ++dc)
            xg[o + dc * 16 + r] = (acc[dc][j] + R[j][dc]) * invl;
    }
}

// ---------------------------------------------------------------------------
extern "C" void kernel_launch(void* const* d_in, const int* in_sizes, int n_in,
                              void* d_out, int out_size, void* d_ws, size_t ws_size,
                              hipStream_t stream) {
    const float* query = (const float*)d_in[0];
    const float* key   = (const float*)d_in[1];
    const float* value = (const float*)d_in[2];
    const float* Wq    = (const float*)d_in[3];
    const float* bq    = (const float*)d_in[4];
    const float* Wk    = (const float*)d_in[5];
    const float* bk    = (const float*)d_in[6];
    const float* Wv    = (const float*)d_in[7];
    const float* bv    = (const float*)d_in[8];
    const float* Wo    = (const float*)d_in[9];
    const float* bo    = (const float*)d_in[10];
    const float* rel_k = (const float*)d_in[11];
    const float* rel_v = (const float*)d_in[12];

    const int B = 2, S = 1024, D = 1024;
    const int M = B * S;
    const size_t elems = (size_t)M * D;

    float* q_ws = (float*)d_ws;
    float* k_ws = q_ws + elems;
    float* v_ws = k_ws + elems;
    float* x_ws = v_ws + elems;

    dim3 ggrid(D / GT, M / GT);
    gemm_bias<<<ggrid, 256, 0, stream>>>(query, Wq, bq, q_ws, M, D, D);
    gemm_bias<<<ggrid, 256, 0, stream>>>(key,   Wk, bk, k_ws, M, D, D);
    gemm_bias<<<ggrid, 256, 0, stream>>>(value, Wv, bv, v_ws, M, D, D);

    attn_mfma<<<512, 256, 0, stream>>>(q_ws, k_ws, v_ws, rel_k, rel_v, x_ws);

    gemm_bias<<<ggrid, 256, 0, stream>>>(x_ws, Wo, bo, (float*)d_out, M, D, D);
}

// Round 7
// 122.038 us; speedup vs baseline: 8.4873x; 3.6813x over previous
//
#include <hip/hip_runtime.h>
#include <math.h>

#define Hh 16
#define DH 64
#define NR 33

typedef short s16x8 __attribute__((ext_vector_type(8)));
typedef float f32x4 __attribute__((ext_vector_type(4)));
typedef __fp16 h16x2 __attribute__((ext_vector_type(2)));

static __device__ __forceinline__ short f2h(float f) {
    _Float16 h = (_Float16)f;              // RNE
    short s; __builtin_memcpy(&s, &h, 2); return s;
}
static __device__ __forceinline__ unsigned pk2h(float a, float b) {
    h16x2 h = __builtin_amdgcn_cvt_pkrtz(a, b);   // packed RTZ, 1 VALU op
    unsigned r; __builtin_memcpy(&r, &h, 4); return r;
}

// MFMA f16, hazard nops inside the asm block (proven pattern from attn):
// the output "+v" dependency orders all consumers after the wait-states.
static __device__ __forceinline__ void mfma16(f32x4& c, const s16x8& a, const s16x8& b) {
    asm("s_nop 3\n\tv_mfma_f32_16x16x32_f16 %0, %1, %2, %0"
        : "+v"(c) : "v"(a), "v"(b));
}
static __device__ __forceinline__ void mfma16_last(f32x4& c, const s16x8& a, const s16x8& b) {
    asm("s_nop 3\n\tv_mfma_f32_16x16x32_f16 %0, %1, %2, %0\n\ts_nop 7\n\ts_nop 7"
        : "+v"(c) : "v"(a), "v"(b));
}
// guard before VALU reads of an MFMA accumulator (data-dep via "+v")
static __device__ __forceinline__ void acc_guard(f32x4& c) {
    asm volatile("s_nop 7\n\ts_nop 7" : "+v"(c));
}

// async global->LDS, 16B per lane; LDS dest = wave-uniform base + lane*16
static __device__ __forceinline__ void gld16(const short* g, short* l) {
    __builtin_amdgcn_global_load_lds(
        (const __attribute__((address_space(1))) void*)g,
        (__attribute__((address_space(3))) void*)l, 16, 0, 0);
}

// swizzled fragment read: LDS[row][x] holds G[row][x ^ ((row&7)<<4)] (bytes)
static __device__ __forceinline__ s16x8 lds_frag(const short* base, int row, int kb) {
    return *(const s16x8*)((const char*)base + row * 128 + (kb ^ ((row & 7) << 4)));
}

// ---------------- weights: fp32 [K][N] -> f16 [N][K] ------------------------
__global__ __launch_bounds__(256)
void cvt_w(const float* __restrict__ W0, const float* __restrict__ W1,
           const float* __restrict__ W2, const float* __restrict__ W3,
           short* __restrict__ Wt) {
    __shared__ float ts[32][33];
    const int z = blockIdx.z;
    const float* W = (z == 0) ? W0 : (z == 1) ? W1 : (z == 2) ? W2 : W3;
    short* O = Wt + (size_t)z * 1024 * 1024;
    const int n0 = blockIdx.x * 32, k0 = blockIdx.y * 32;
    const int tx = threadIdx.x & 31, ty = threadIdx.x >> 5;
    #pragma unroll
    for (int rr = 0; rr < 4; ++rr)
        ts[ty + 8 * rr][tx] = W[(size_t)(k0 + ty + 8 * rr) * 1024 + n0 + tx];
    __syncthreads();
    #pragma unroll
    for (int rr = 0; rr < 4; ++rr)
        O[(size_t)(n0 + ty + 8 * rr) * 1024 + k0 + tx] = f2h(ts[tx][ty + 8 * rr]);
}

// ---------------- fused QKV projection: f16 MFMA ---------------------------
// BM=64 BN=128 BK=64, 256 thr (2x2 waves, wave tile 32x64). A: fp32 global ->
// cvt_pkrtz -> swizzled ds_write. B: Wt f16 via global_load_lds with
// inverse-swizzled per-lane SOURCE (linear LDS dest). Out: f16.
__global__ __launch_bounds__(256)
void gemm_qkv(const float* __restrict__ Aq, const float* __restrict__ Ak,
              const float* __restrict__ Av, const short* __restrict__ Wt,
              const float* __restrict__ bq, const float* __restrict__ bk,
              const float* __restrict__ bv, short* __restrict__ Out) {
    __shared__ __align__(16) short As[64 * 64];
    __shared__ __align__(16) short Bs[128 * 64];
    const int tid = threadIdx.x;
    const int wave = tid >> 6, lane = tid & 63;
    const int g = lane >> 4, r = lane & 15;
    const int wm = wave >> 1, wn = wave & 1;
    const int n0 = blockIdx.x * 128;
    const int by = blockIdx.y;
    const int slab = by >> 5;                 // 0:q 1:k 2:v
    const int m0 = (by & 31) * 64;
    const float* A    = (slab == 0) ? Aq : (slab == 1) ? Ak : Av;
    const float* bias = (slab == 0) ? bq : (slab == 1) ? bk : bv;
    const short* Bg = Wt + (size_t)slab * 1024 * 1024;
    short* Og = Out + (size_t)slab * 2048 * 1024;

    // A staging: thread -> (row = tid>>2, 16 floats at k = (tid&3)*16)
    const int ar = tid >> 2, ak = tid & 3;
    const float* ap = A + (size_t)(m0 + ar) * 1024 + ak * 16;
    char* asb = (char*)As + ar * 128;
    const int aswz = (ar & 7) << 4;
    const int ao0 = (ak * 32) ^ aswz, ao1 = (ak * 32 + 16) ^ aswz;

    // B staging slots: s = i*256+tid -> row = s>>3, 16B chunk sk = s&7
    const short* bp[4]; short* bl[4];
    #pragma unroll
    for (int i = 0; i < 4; ++i) {
        int s = i * 256 + tid;
        int row = s >> 3, sk = s & 7;
        int gb = (sk * 16) ^ ((row & 7) << 4);        // inverse-swizzled source
        bp[i] = Bg + (size_t)(n0 + row) * 1024 + gb / 2;
        bl[i] = Bs + (size_t)(i * 256 + wave * 64) * 8;
    }

    f32x4 acc[2][4] = {};
    #pragma unroll
    for (int mi = 0; mi < 2; ++mi)
        #pragma unroll
        for (int nj = 0; nj < 4; ++nj)
            asm volatile("s_nop 7" : "+v"(acc[mi][nj]));  // VALU-init -> SrcC guard

    for (int kt = 0; kt < 1024; kt += 64) {
        #pragma unroll
        for (int i = 0; i < 4; ++i) gld16(bp[i] + kt, bl[i]);
        float4 va[4];
        #pragma unroll
        for (int c = 0; c < 4; ++c) va[c] = *(const float4*)(ap + kt + c * 4);
        unsigned pk[8];
        #pragma unroll
        for (int c = 0; c < 4; ++c) {
            pk[2 * c]     = pk2h(va[c].x, va[c].y);
            pk[2 * c + 1] = pk2h(va[c].z, va[c].w);
        }
        *(uint4*)(asb + ao0) = *(const uint4*)&pk[0];
        *(uint4*)(asb + ao1) = *(const uint4*)&pk[4];
        asm volatile("s_waitcnt vmcnt(0)" ::: "memory");
        __syncthreads();
        #pragma unroll
        for (int ks = 0; ks < 2; ++ks) {
            s16x8 af[2], bf[4];
            #pragma unroll
            for (int mi = 0; mi < 2; ++mi)
                af[mi] = lds_frag(As, wm * 32 + mi * 16 + r, ks * 64 + g * 16);
            #pragma unroll
            for (int nj = 0; nj < 4; ++nj)
                bf[nj] = lds_frag(Bs, wn * 64 + nj * 16 + r, ks * 64 + g * 16);
            #pragma unroll
            for (int mi = 0; mi < 2; ++mi)
                #pragma unroll
                for (int nj = 0; nj < 4; ++nj)
                    mfma16(acc[mi][nj], af[mi], bf[nj]);
        }
        __syncthreads();
    }
    #pragma unroll
    for (int nj = 0; nj < 4; ++nj) {
        int col = n0 + wn * 64 + nj * 16 + r;
        float bv_ = bias[col];
        #pragma unroll
        for (int mi = 0; mi < 2; ++mi) {
            acc_guard(acc[mi][nj]);
            #pragma unroll
            for (int j = 0; j < 4; ++j) {
                int row = m0 + wm * 32 + mi * 16 + g * 4 + j;
                Og[(size_t)row * 1024 + col] = f2h(acc[mi][nj][j] + bv_);
            }
        }
    }
}

// ---------------- output projection: x(f16) @ Wo_t(f16) + bo -> fp32 --------
__global__ __launch_bounds__(256)
void gemm_out(const short* __restrict__ Xg, const short* __restrict__ Bg,
              const float* __restrict__ bo, float* __restrict__ Og) {
    __shared__ __align__(16) short As[64 * 64];
    __shared__ __align__(16) short Bs[128 * 64];
    const int tid = threadIdx.x;
    const int wave = tid >> 6, lane = tid & 63;
    const int g = lane >> 4, r = lane & 15;
    const int wm = wave >> 1, wn = wave & 1;
    const int n0 = blockIdx.x * 128;
    const int m0 = blockIdx.y * 64;

    const short* xp[2]; short* xl[2];
    #pragma unroll
    for (int i = 0; i < 2; ++i) {
        int s = i * 256 + tid;
        int row = s >> 3, sk = s & 7;
        int gb = (sk * 16) ^ ((row & 7) << 4);
        xp[i] = Xg + (size_t)(m0 + row) * 1024 + gb / 2;
        xl[i] = As + (size_t)(i * 256 + wave * 64) * 8;
    }
    const short* bp[4]; short* bl[4];
    #pragma unroll
    for (int i = 0; i < 4; ++i) {
        int s = i * 256 + tid;
        int row = s >> 3, sk = s & 7;
        int gb = (sk * 16) ^ ((row & 7) << 4);
        bp[i] = Bg + (size_t)(n0 + row) * 1024 + gb / 2;
        bl[i] = Bs + (size_t)(i * 256 + wave * 64) * 8;
    }

    f32x4 acc[2][4] = {};
    #pragma unroll
    for (int mi = 0; mi < 2; ++mi)
        #pragma unroll
        for (int nj = 0; nj < 4; ++nj)
            asm volatile("s_nop 7" : "+v"(acc[mi][nj]));

    for (int kt = 0; kt < 1024; kt += 64) {
        #pragma unroll
        for (int i = 0; i < 2; ++i) gld16(xp[i] + kt, xl[i]);
        #pragma unroll
        for (int i = 0; i < 4; ++i) gld16(bp[i] + kt, bl[i]);
        asm volatile("s_waitcnt vmcnt(0)" ::: "memory");
        __syncthreads();
        #pragma unroll
        for (int ks = 0; ks < 2; ++ks) {
            s16x8 af[2], bf[4];
            #pragma unroll
            for (int mi = 0; mi < 2; ++mi)
                af[mi] = lds_frag(As, wm * 32 + mi * 16 + r, ks * 64 + g * 16);
            #pragma unroll
            for (int nj = 0; nj < 4; ++nj)
                bf[nj] = lds_frag(Bs, wn * 64 + nj * 16 + r, ks * 64 + g * 16);
            #pragma unroll
            for (int mi = 0; mi < 2; ++mi)
                #pragma unroll
                for (int nj = 0; nj < 4; ++nj)
                    mfma16(acc[mi][nj], af[mi], bf[nj]);
        }
        __syncthreads();
    }
    #pragma unroll
    for (int nj = 0; nj < 4; ++nj) {
        int col = n0 + wn * 64 + nj * 16 + r;
        float bv_ = bo[col];
        #pragma unroll
        for (int mi = 0; mi < 2; ++mi) {
            acc_guard(acc[mi][nj]);
            #pragma unroll
            for (int j = 0; j < 4; ++j) {
                int row = m0 + wm * 32 + mi * 16 + g * 4 + j;
                Og[(size_t)row * 1024 + col] = acc[mi][nj][j] + bv_;
            }
        }
    }
}

// ---------------- MFMA attention (f16 in / f16 x out) -----------------------
#define KSTR 72
#define QRSTR 49
#define RVSTR 68

__global__ __launch_bounds__(256)
void attn_mfma(const short* __restrict__ qg, const short* __restrict__ kg,
               const short* __restrict__ vg, const float* __restrict__ relk,
               const float* __restrict__ relv, short* __restrict__ xg) {
    __shared__ __align__(16) short k_s[64 * KSTR];
    __shared__ __align__(16) short vt_s[64 * KSTR];
    __shared__ __align__(16) short p_s[4][16 * KSTR];
    __shared__ float qr_s[64 * QRSTR];
    __shared__ float W_s[64 * NR];
    __shared__ __align__(16) unsigned char relbuf[NR * RVSTR * 4];

    short* rel_h = (short*)relbuf;    // [48][KSTR] f16 (start of block)
    float* rv_s  = (float*)relbuf;    // [33][RVSTR] fp32 (epilogue)

    const int S = 1024, Dm = 1024;
    const int tid = threadIdx.x;
    const int wave = tid >> 6;
    const int lane = tid & 63;
    const int g = lane >> 4;
    const int r = lane & 15;

    const int blk = blockIdx.x;
    const int bh = blk & 31;
    const int qb = blk >> 5;
    const int b = bh >> 4, h = bh & 15;
    const size_t base = (size_t)b * S * Dm + h * DH;
    const int qw = qb * 64 + wave * 16;

    for (int idx = tid; idx < 48 * 64; idx += 256) {
        int row = idx >> 6, col = idx & 63;
        float val = (row < NR) ? relk[row * 64 + col] : 0.f;
        rel_h[row * KSTR + col] = f2h(val);
    }
    for (int idx = tid; idx < 64 * NR; idx += 256) W_s[idx] = 0.f;
    __syncthreads();

    // Q fragments: raw f16 (scale applied after MFMA)
    s16x8 qf[2];
    qf[0] = *(const s16x8*)(qg + base + (size_t)(qw + r) * Dm + g * 8);
    qf[1] = *(const s16x8*)(qg + base + (size_t)(qw + r) * Dm + 32 + g * 8);

    // qr[q][bucket] = q . relk[bucket] (raw)
    #pragma unroll
    for (int ct = 0; ct < 3; ++ct) {
        f32x4 c = {0.f, 0.f, 0.f, 0.f};
        s16x8 bf0 = *(const s16x8*)&rel_h[(ct * 16 + r) * KSTR + g * 8];
        s16x8 bf1 = *(const s16x8*)&rel_h[(ct * 16 + r) * KSTR + 32 + g * 8];
        mfma16(c, qf[0], bf0);
        mfma16_last(c, qf[1], bf1);
        #pragma unroll
        for (int j = 0; j < 4; ++j)
            qr_s[(wave * 16 + g * 4 + j) * QRSTR + ct * 16 + r] = c[j];
    }

    f32x4 acc[4] = {};
    float l_acc[4] = {0.f, 0.f, 0.f, 0.f};
    float pre[4]   = {0.f, 0.f, 0.f, 0.f};
    float suf[4]   = {0.f, 0.f, 0.f, 0.f};
    const float SCL = 0.18033688f;   // log2(e)/sqrt(dh)

    for (int kt = 0; kt < S; kt += 64) {
        __syncthreads();
        #pragma unroll
        for (int i = 0; i < 2; ++i) {
            int idx = tid + 256 * i;
            int row = idx >> 3, c8 = idx & 7;
            s16x8 kv = *(const s16x8*)(kg + base + (size_t)(kt + row) * Dm + c8 * 8);
            s16x8 vv = *(const s16x8*)(vg + base + (size_t)(kt + row) * Dm + c8 * 8);
            *(s16x8*)&k_s[row * KSTR + c8 * 8] = kv;
            #pragma unroll
            for (int e = 0; e < 8; ++e) vt_s[(c8 * 8 + e) * KSTR + row] = vv[e];
        }
        __syncthreads();

        #pragma unroll
        for (int kc = 0; kc < 4; ++kc) {
            f32x4 s = {0.f, 0.f, 0.f, 0.f};
            s16x8 k0 = *(const s16x8*)&k_s[(kc * 16 + r) * KSTR + g * 8];
            s16x8 k1 = *(const s16x8*)&k_s[(kc * 16 + r) * KSTR + 32 + g * 8];
            mfma16(s, qf[0], k0);
            mfma16_last(s, qf[1], k1);
            int k_abs = kt + kc * 16 + r;
            #pragma unroll
            for (int j = 0; j < 4; ++j) {
                int qrow = wave * 16 + g * 4 + j;
                int dist = k_abs - (qb * 64 + qrow);
                int bkt = min(max(dist, -16), 16) + 16;
                float val = (s[j] + qr_s[qrow * QRSTR + bkt]) * SCL;
                float p = exp2f(val);
                l_acc[j] += p;
                if (dist <= -16)      pre[j] += p;
                else if (dist >= 16)  suf[j] += p;
                else                  W_s[qrow * NR + bkt] = p;
                p_s[wave][(g * 4 + j) * KSTR + kc * 16 + r] = f2h(p);
            }
        }

        s16x8 pa0 = *(const s16x8*)&p_s[wave][r * KSTR + g * 8];
        s16x8 pa1 = *(const s16x8*)&p_s[wave][r * KSTR + 32 + g * 8];
        #pragma unroll
        for (int dc = 0; dc < 4; ++dc) {
            s16x8 v0 = *(const s16x8*)&vt_s[(dc * 16 + r) * KSTR + g * 8];
            s16x8 v1 = *(const s16x8*)&vt_s[(dc * 16 + r) * KSTR + 32 + g * 8];
            mfma16(acc[dc], pa0, v0);
            mfma16(acc[dc], pa1, v1);
        }
    }

    #pragma unroll
    for (int j = 0; j < 4; ++j) {
        #pragma unroll
        for (int m = 1; m < 16; m <<= 1) {
            l_acc[j] += __shfl_xor(l_acc[j], m, 16);
            pre[j]   += __shfl_xor(pre[j], m, 16);
            suf[j]   += __shfl_xor(suf[j], m, 16);
        }
    }
    if (r == 0) {
        #pragma unroll
        for (int j = 0; j < 4; ++j) {
            int qrow = wave * 16 + g * 4 + j;
            W_s[qrow * NR + 0]  = pre[j];
            W_s[qrow * NR + 32] = suf[j];
        }
    }

    __syncthreads();
    for (int idx = tid; idx < NR * 64; idx += 256)
        rv_s[(idx >> 6) * RVSTR + (idx & 63)] = relv[idx];
    __syncthreads();

    float R[4][4] = {};
    for (int rr = 0; rr < NR; ++rr) {
        float rvv[4];
        #pragma unroll
        for (int dc = 0; dc < 4; ++dc) rvv[dc] = rv_s[rr * RVSTR + dc * 16 + r];
        #pragma unroll
        for (int j = 0; j < 4; ++j) {
            float w = W_s[(wave * 16 + g * 4 + j) * NR + rr];
            #pragma unroll
            for (int dc = 0; dc < 4; ++dc) R[j][dc] = fmaf(w, rvv[dc], R[j][dc]);
        }
    }
    #pragma unroll
    for (int dc = 0; dc < 4; ++dc) acc_guard(acc[dc]);
    #pragma unroll
    for (int j = 0; j < 4; ++j) {
        float invl = 1.f / l_acc[j];
        size_t o = base + (size_t)(qw + g * 4 + j) * Dm;
        #pragma unroll
        for (int dc = 0; dc < 4; ++dc)
            xg[o + dc * 16 + r] = f2h((acc[dc][j] + R[j][dc]) * invl);
    }
}

// ---------------------------------------------------------------------------
extern "C" void kernel_launch(void* const* d_in, const int* in_sizes, int n_in,
                              void* d_out, int out_size, void* d_ws, size_t ws_size,
                              hipStream_t stream) {
    const float* query = (const float*)d_in[0];
    const float* key   = (const float*)d_in[1];
    const float* value = (const float*)d_in[2];
    const float* Wq    = (const float*)d_in[3];
    const float* bq    = (const float*)d_in[4];
    const float* Wk    = (const float*)d_in[5];
    const float* bk    = (const float*)d_in[6];
    const float* Wv    = (const float*)d_in[7];
    const float* bv    = (const float*)d_in[8];
    const float* Wo    = (const float*)d_in[9];
    const float* bo    = (const float*)d_in[10];
    const float* rel_k = (const float*)d_in[11];
    const float* rel_v = (const float*)d_in[12];

    // workspace (f16): Wt 8MB | q/k/v 12MB | x 4MB  = 24MB
    short* wt    = (short*)d_ws;
    short* qkv16 = wt + (size_t)4 * 1024 * 1024;
    short* x16   = qkv16 + (size_t)3 * 2048 * 1024;
    short* q16 = qkv16;
    short* k16 = qkv16 + (size_t)2048 * 1024;
    short* v16 = qkv16 + (size_t)2 * 2048 * 1024;

    cvt_w<<<dim3(32, 32, 4), 256, 0, stream>>>(Wq, Wk, Wv, Wo, wt);
    gemm_qkv<<<dim3(8, 96), 256, 0, stream>>>(query, key, value, wt,
                                              bq, bk, bv, qkv16);
    attn_mfma<<<512, 256, 0, stream>>>(q16, k16, v16, rel_k, rel_v, x16);
    gemm_out<<<dim3(8, 32), 256, 0, stream>>>(x16, wt + (size_t)3 * 1024 * 1024,
                                              bo, (float*)d_out);
}